// Round 1
// baseline (2727.965 us; speedup 1.0000x reference)
//
#include <hip/hip_runtime.h>

// Fused 2-layer LSTM (H=64) + Dense(64,sigmoid) + Dense(1,sigmoid).
// B=4096, T=256, F=32. One WG of 256 threads handles BB=8 batch rows.
// Thread j owns gate-column j (gate = j>>6 in {i,f,g,o}, unit = j&63).
// U1/W2/U2 columns live in registers (192 VGPR), W1 in LDS.
// h/c state exchanged via LDS with [k][bb] layouts for float4 broadcast reads.

__device__ __forceinline__ float ex2(float x)  { return __builtin_amdgcn_exp2f(x); }
__device__ __forceinline__ float rcpf_(float x){ return __builtin_amdgcn_rcpf(x); }
// sigmoid(x) = 1/(1+2^(-x*log2 e)); safe at +-inf (exp2->inf => 0, exp2->0 => 1)
__device__ __forceinline__ float sigm(float x) { return rcpf_(1.0f + ex2(-1.44269504f * x)); }
// tanh(x) = 1 - 2/(2^(2x*log2 e)+1); safe for large |x| (no inf/inf)
__device__ __forceinline__ float tanh_(float x){ return 1.0f - 2.0f * rcpf_(1.0f + ex2(2.88539008f * x)); }

#define ACC8(Z, A0, A1, Wt) do{ \
    Z[0]=fmaf((A0).x,(Wt),Z[0]); Z[1]=fmaf((A0).y,(Wt),Z[1]); \
    Z[2]=fmaf((A0).z,(Wt),Z[2]); Z[3]=fmaf((A0).w,(Wt),Z[3]); \
    Z[4]=fmaf((A1).x,(Wt),Z[4]); Z[5]=fmaf((A1).y,(Wt),Z[5]); \
    Z[6]=fmaf((A1).z,(Wt),Z[6]); Z[7]=fmaf((A1).w,(Wt),Z[7]); }while(0)

__global__ __launch_bounds__(256, 1)
void lstm2_fused(const float* __restrict__ x,
                 const float* __restrict__ W1, const float* __restrict__ U1, const float* __restrict__ b1,
                 const float* __restrict__ W2, const float* __restrict__ U2, const float* __restrict__ b2,
                 const float* __restrict__ Wd, const float* __restrict__ bd,
                 const float* __restrict__ Wo, const float* __restrict__ bo,
                 float* __restrict__ out)
{
    __shared__ float  W1s[32 * 256];     // 32 KB; reused for Wd in epilogue
    __shared__ float4 xs [32][2];        // x_t transposed: [f][bb]  (8 floats/row)
    __shared__ float4 h1s[64][2];        // layer-1 hidden: [k][bb]
    __shared__ float4 h2s[64][2];        // layer-2 hidden: [k][bb]
    __shared__ float4 gsv[8][64];        // gate exchange: [bb][unit] = (i,f,g,o)
    __shared__ float  dsm[8][64];        // dense1 output

    const int j    = threadIdx.x;
    const int gate = j >> 6;             // wave index: 0=i,1=f,2=g(tanh),3=o
    const int unit = j & 63;
    const int b0   = blockIdx.x * 8;

    // ---- weight columns -> registers (coalesced: lane j reads row k, col j) ----
    float U1c[64], W2c[64], U2c[64];
#pragma unroll
    for (int k = 0; k < 64; ++k) {
        U1c[k] = U1[k * 256 + j];
        W2c[k] = W2[k * 256 + j];
        U2c[k] = U2[k * 256 + j];
    }
    const float b1j = b1[j], b2j = b2[j];

#pragma unroll
    for (int i = 0; i < 32; ++i) W1s[i * 256 + j] = W1[i * 256 + j];

    // zero h state (512 floats each)
    ((float*)h1s)[j] = 0.0f; ((float*)h1s)[j + 256] = 0.0f;
    ((float*)h2s)[j] = 0.0f; ((float*)h2s)[j + 256] = 0.0f;
    // c state owned by this thread: pairs (bb=gate, unit) and (bb=gate+4, unit)
    float c1a = 0.0f, c1b = 0.0f, c2a = 0.0f, c2b = 0.0f;

    // x prefetch: thread loads element (bb = j>>5, f = j&31) of step t
    const int bbx = j >> 5, fx = j & 31;
    const float* xp = x + (size_t)(b0 + bbx) * 8192 + fx;   // T*F = 8192
    float xreg = xp[0];

    for (int t = 0; t < 256; ++t) {
        // publish x_t, then prefetch x_{t+1} (latency hides under this step)
        ((float*)xs)[fx * 8 + bbx] = xreg;
        __syncthreads();                                   // B1
        if (t < 255) xreg = xp[(t + 1) * 32];

        // ---- layer 1 gate pre-activations: z = b1 + x@W1 + h1@U1 ----
        float z[8];
#pragma unroll
        for (int bb = 0; bb < 8; ++bb) z[bb] = b1j;
#pragma unroll
        for (int f = 0; f < 32; ++f) {
            float w = W1s[f * 256 + j];                    // stride-1, conflict-free
            float4 a0 = xs[f][0], a1 = xs[f][1];           // broadcast b128
            ACC8(z, a0, a1, w);
        }
#pragma unroll
        for (int k = 0; k < 64; ++k) {
            float u = U1c[k];
            float4 a0 = h1s[k][0], a1 = h1s[k][1];
            ACC8(z, a0, a1, u);
        }
        // activation (wave-uniform branch) + publish gates
        if (gate == 2) {
#pragma unroll
            for (int bb = 0; bb < 8; ++bb) ((float*)&gsv[bb][unit])[2] = tanh_(z[bb]);
        } else {
#pragma unroll
            for (int bb = 0; bb < 8; ++bb) ((float*)&gsv[bb][unit])[gate] = sigm(z[bb]);
        }
        __syncthreads();                                   // B2

        // ---- layer-1 state update for (bb=gate, unit) and (bb=gate+4, unit) ----
        {
            float4 ga = gsv[gate][unit];
            float4 gb = gsv[gate + 4][unit];
            c1a = fmaf(ga.y, c1a, ga.x * ga.z);
            c1b = fmaf(gb.y, c1b, gb.x * gb.z);
            ((float*)h1s)[unit * 8 + gate]     = ga.w * tanh_(c1a);
            ((float*)h1s)[unit * 8 + gate + 4] = gb.w * tanh_(c1b);
        }
        __syncthreads();                                   // B3

        // ---- layer 2: z = b2 + h1_t@W2 + h2_{t-1}@U2 ----
#pragma unroll
        for (int bb = 0; bb < 8; ++bb) z[bb] = b2j;
#pragma unroll
        for (int k = 0; k < 64; ++k) {
            float w = W2c[k], u = U2c[k];
            float4 a0 = h1s[k][0], a1 = h1s[k][1];
            ACC8(z, a0, a1, w);
            float4 d0 = h2s[k][0], d1 = h2s[k][1];
            ACC8(z, d0, d1, u);
        }
        if (gate == 2) {
#pragma unroll
            for (int bb = 0; bb < 8; ++bb) ((float*)&gsv[bb][unit])[2] = tanh_(z[bb]);
        } else {
#pragma unroll
            for (int bb = 0; bb < 8; ++bb) ((float*)&gsv[bb][unit])[gate] = sigm(z[bb]);
        }
        __syncthreads();                                   // B4

        {
            float4 ga = gsv[gate][unit];
            float4 gb = gsv[gate + 4][unit];
            c2a = fmaf(ga.y, c2a, ga.x * ga.z);
            c2b = fmaf(gb.y, c2b, gb.x * gb.z);
            ((float*)h2s)[unit * 8 + gate]     = ga.w * tanh_(c2a);
            ((float*)h2s)[unit * 8 + gate + 4] = gb.w * tanh_(c2b);
        }
        // no barrier here: next-iter B1 orders gsv/h2s hazards
    }
    __syncthreads();

    // ---- epilogue: Dense(64, sigmoid) then Dense(1, sigmoid) ----
#pragma unroll
    for (int i = 0; i < 16; ++i) W1s[i * 256 + j] = Wd[i * 256 + j];   // 64x64 into W1s
    const float bdu = bd[unit];
    __syncthreads();
    {
        float s0 = bdu, s1 = bdu;
#pragma unroll
        for (int k = 0; k < 64; ++k) {
            float w = W1s[k * 64 + unit];                  // stride-1
            s0 = fmaf(((const float*)h2s)[k * 8 + gate],     w, s0);   // broadcast
            s1 = fmaf(((const float*)h2s)[k * 8 + gate + 4], w, s1);
        }
        dsm[gate][unit]     = sigm(s0);
        dsm[gate + 4][unit] = sigm(s1);
    }
    __syncthreads();
    {
        float wo = Wo[unit];
        float p0 = dsm[gate][unit]     * wo;
        float p1 = dsm[gate + 4][unit] * wo;
#pragma unroll
        for (int off = 32; off > 0; off >>= 1) {
            p0 += __shfl_xor(p0, off, 64);
            p1 += __shfl_xor(p1, off, 64);
        }
        if (unit == 0) {
            float bo0 = bo[0];
            out[b0 + gate]     = sigm(p0 + bo0);
            out[b0 + gate + 4] = sigm(p1 + bo0);
        }
    }
}

extern "C" void kernel_launch(void* const* d_in, const int* in_sizes, int n_in,
                              void* d_out, int out_size, void* d_ws, size_t ws_size,
                              hipStream_t stream) {
    (void)in_sizes; (void)n_in; (void)d_ws; (void)ws_size; (void)out_size;
    const float* x  = (const float*)d_in[0];
    const float* W1 = (const float*)d_in[1];
    const float* U1 = (const float*)d_in[2];
    const float* b1 = (const float*)d_in[3];
    const float* W2 = (const float*)d_in[4];
    const float* U2 = (const float*)d_in[5];
    const float* b2 = (const float*)d_in[6];
    const float* Wd = (const float*)d_in[7];
    const float* bd = (const float*)d_in[8];
    const float* Wo = (const float*)d_in[9];
    const float* bo = (const float*)d_in[10];
    lstm2_fused<<<dim3(512), dim3(256), 0, stream>>>(
        x, W1, U1, b1, W2, U2, b2, Wd, bd, Wo, bo, (float*)d_out);
}

// Round 2
// 455.234 us; speedup vs baseline: 5.9924x; 5.9924x over previous
//
#include <hip/hip_runtime.h>

// Fused 2-layer LSTM (H=64) + Dense(64,sigmoid) + Dense(1,sigmoid), MFMA bf16.
// B=4096, T=256, F=32. One WG = 256 threads = 4 waves handles BB=16 batch rows.
// Per step: GEMM1 z1[16,256] = [x_t | h1] @ [W1;U1]  (K=96, 3 K-chunks)
//           GEMM2 z2[16,256] = [h1_t | h2] @ [W2;U2] (K=128, 4 K-chunks)
// Wave w owns units [16w,16w+16) in ALL 4 gates -> i,f,g,o for a (row,unit)
// live in one lane's 4 accumulators; cell update is register-local.
// h1/h2 round-trip LDS as bf16, row stride 72 shorts (conflict-free b128).
// Weight B-fragments live in registers (28 short8 = 112 VGPR).
// MFMA 16x16x32 layouts (learn_hip-verified):
//   A[m=lane&15][k=(lane>>4)*8+j], B[k=(lane>>4)*8+j][n=lane&15],
//   C/D: col=lane&15, row=(lane>>4)*4+reg.

typedef __attribute__((ext_vector_type(8))) short short8;
typedef __attribute__((ext_vector_type(4))) float floatx4;
typedef __attribute__((ext_vector_type(2))) float floatx2;

__device__ __forceinline__ float ex2(float x){ return __builtin_amdgcn_exp2f(x); }
__device__ __forceinline__ float rcp_(float x){ return __builtin_amdgcn_rcpf(x); }
__device__ __forceinline__ float sigm(float x){ return rcp_(1.0f + ex2(-1.44269504f*x)); }
__device__ __forceinline__ float tanh_(float x){ return 1.0f - 2.0f*rcp_(1.0f + ex2(2.88539008f*x)); }
__device__ __forceinline__ short f2bf(float f){            // RNE f32->bf16
    unsigned u = __builtin_bit_cast(unsigned, f);
    u += 0x7FFFu + ((u >> 16) & 1u);
    return (short)(u >> 16);
}

__global__ __launch_bounds__(256, 1)
void lstm2_mfma(const float* __restrict__ x,
                const float* __restrict__ W1, const float* __restrict__ U1, const float* __restrict__ b1,
                const float* __restrict__ W2, const float* __restrict__ U2, const float* __restrict__ b2,
                const float* __restrict__ Wd, const float* __restrict__ bd,
                const float* __restrict__ Wo, const float* __restrict__ bo,
                float* __restrict__ out)
{
    __shared__ __align__(16) short h1b[2][16 * 72];   // [buf][row*72 + unit]
    __shared__ __align__(16) short h2b[2][16 * 72];
    __shared__ __align__(16) short xsb[2][16 * 40];   // [buf][row*40 + f]
    __shared__ float psum[4][16];

    const int tid  = threadIdx.x;
    const int w    = tid >> 6;        // wave: units [16w,16w+16)
    const int lane = tid & 63;
    const int m    = lane & 15;       // A/C row index, or col-in-tile
    const int q    = lane >> 4;       // quad
    const int b0   = blockIdx.x * 16;
    const int col  = w * 16 + m;      // unit 0..63

    // ---- one-time: weight B-fragments -> registers (bf16) ----
    short8 B1f[4][3], B2f[4][4];
    float b1g[4], b2g[4];
#pragma unroll
    for (int g = 0; g < 4; ++g) {
        const int n = g * 64 + col;
        b1g[g] = b1[n];
        b2g[g] = b2[n];
#pragma unroll
        for (int j = 0; j < 8; ++j) {
            const int k = q * 8 + j;
            B1f[g][0][j] = f2bf(W1[k * 256 + n]);          // K-chunk0: x @ W1
            B1f[g][1][j] = f2bf(U1[k * 256 + n]);          // K-chunk1: h1[0:32) @ U1
            B1f[g][2][j] = f2bf(U1[(32 + k) * 256 + n]);   // K-chunk2: h1[32:64)
            B2f[g][0][j] = f2bf(W2[k * 256 + n]);
            B2f[g][1][j] = f2bf(W2[(32 + k) * 256 + n]);
            B2f[g][2][j] = f2bf(U2[k * 256 + n]);
            B2f[g][3][j] = f2bf(U2[(32 + k) * 256 + n]);
        }
    }

    // ---- zero h buffers (both halves of both double-buffers) ----
    {
        unsigned* p1 = (unsigned*)&h1b[0][0];
        unsigned* p2 = (unsigned*)&h2b[0][0];
        for (int i = tid; i < 1152; i += 256) { p1[i] = 0u; p2[i] = 0u; }
    }

    // ---- x_0 -> xsb[0]; thread loads 2 fp32 of row (tid>>4) ----
    const int xr = tid >> 4;
    const int xc = (tid & 15) * 2;
    const float* xrow = x + (size_t)(b0 + xr) * 8192 + xc;   // T*F = 8192
    {
        floatx2 v = *(const floatx2*)xrow;
        unsigned pk = (unsigned)(unsigned short)f2bf(v.x)
                    | ((unsigned)(unsigned short)f2bf(v.y) << 16);
        *(unsigned*)&xsb[0][xr * 40 + xc] = pk;
    }
    __syncthreads();

    float c1[4] = {0, 0, 0, 0}, c2[4] = {0, 0, 0, 0};

    for (int t = 0; t < 256; ++t) {
        const int tb = t & 1, t1 = tb ^ 1;

        // prefetch x_{t+1} (consumed after next barrier pair)
        floatx2 xv;
        if (t < 255) xv = *(const floatx2*)(xrow + (t + 1) * 32);

        // ---- GEMM1: z = b1 + [x_t | h1_{t-1}] @ [W1;U1] ----
        short8 a0 = *(const short8*)&xsb[tb][m * 40 + q * 8];
        short8 a1 = *(const short8*)&h1b[tb][m * 72 + q * 8];
        short8 a2 = *(const short8*)&h1b[tb][m * 72 + 32 + q * 8];
        floatx4 z[4];
#pragma unroll
        for (int g = 0; g < 4; ++g) {
            floatx4 acc = { b1g[g], b1g[g], b1g[g], b1g[g] };
            acc = __builtin_amdgcn_mfma_f32_16x16x32_bf16(a0, B1f[g][0], acc, 0, 0, 0);
            acc = __builtin_amdgcn_mfma_f32_16x16x32_bf16(a1, B1f[g][1], acc, 0, 0, 0);
            acc = __builtin_amdgcn_mfma_f32_16x16x32_bf16(a2, B1f[g][2], acc, 0, 0, 0);
            z[g] = acc;
        }
        // gate math layer 1: lane owns rows q*4+r of unit `col`
#pragma unroll
        for (int r = 0; r < 4; ++r) {
            float iv = sigm(z[0][r]);
            float fv = sigm(z[1][r]);
            float gv = tanh_(z[2][r]);
            float ov = sigm(z[3][r]);
            c1[r] = fmaf(fv, c1[r], iv * gv);
            float hv = ov * tanh_(c1[r]);
            h1b[t1][(q * 4 + r) * 72 + col] = f2bf(hv);
        }
        // stash x prefetch into the other buffer (visible after B1/B2)
        if (t < 255) {
            unsigned pk = (unsigned)(unsigned short)f2bf(xv.x)
                        | ((unsigned)(unsigned short)f2bf(xv.y) << 16);
            *(unsigned*)&xsb[t1][xr * 40 + xc] = pk;
        }
        __syncthreads();   // B1: h1[t1] visible to all waves

        // ---- GEMM2: z = b2 + [h1_t | h2_{t-1}] @ [W2;U2] ----
        short8 g0 = *(const short8*)&h1b[t1][m * 72 + q * 8];
        short8 g1 = *(const short8*)&h1b[t1][m * 72 + 32 + q * 8];
        short8 g2 = *(const short8*)&h2b[tb][m * 72 + q * 8];
        short8 g3 = *(const short8*)&h2b[tb][m * 72 + 32 + q * 8];
#pragma unroll
        for (int g = 0; g < 4; ++g) {
            floatx4 acc = { b2g[g], b2g[g], b2g[g], b2g[g] };
            acc = __builtin_amdgcn_mfma_f32_16x16x32_bf16(g0, B2f[g][0], acc, 0, 0, 0);
            acc = __builtin_amdgcn_mfma_f32_16x16x32_bf16(g1, B2f[g][1], acc, 0, 0, 0);
            acc = __builtin_amdgcn_mfma_f32_16x16x32_bf16(g2, B2f[g][2], acc, 0, 0, 0);
            acc = __builtin_amdgcn_mfma_f32_16x16x32_bf16(g3, B2f[g][3], acc, 0, 0, 0);
            z[g] = acc;
        }
#pragma unroll
        for (int r = 0; r < 4; ++r) {
            float iv = sigm(z[0][r]);
            float fv = sigm(z[1][r]);
            float gv = tanh_(z[2][r]);
            float ov = sigm(z[3][r]);
            c2[r] = fmaf(fv, c2[r], iv * gv);
            float hv = ov * tanh_(c2[r]);
            h2b[t1][(q * 4 + r) * 72 + col] = f2bf(hv);
        }
        __syncthreads();   // B2: h2[t1] visible; safe to overwrite tb next step
    }

    // ---- epilogue: h_last = h2b[0] (t=255 wrote buffer 0) ----
    // Dense(64,sigmoid): wave w computes output cols [16w,16w+16), K=64
    short8 wd0, wd1;
#pragma unroll
    for (int j = 0; j < 8; ++j) {
        wd0[j] = f2bf(Wd[(q * 8 + j) * 64 + col]);
        wd1[j] = f2bf(Wd[(32 + q * 8 + j) * 64 + col]);
    }
    short8 hA0 = *(const short8*)&h2b[0][m * 72 + q * 8];
    short8 hA1 = *(const short8*)&h2b[0][m * 72 + 32 + q * 8];
    float bdv = bd[col];
    floatx4 dacc = { bdv, bdv, bdv, bdv };
    dacc = __builtin_amdgcn_mfma_f32_16x16x32_bf16(hA0, wd0, dacc, 0, 0, 0);
    dacc = __builtin_amdgcn_mfma_f32_16x16x32_bf16(hA1, wd1, dacc, 0, 0, 0);

    // Dense(1,sigmoid): p[row] = sum_units sigm(d[row][unit]) * Wo[unit]
    float wo = Wo[col];
#pragma unroll
    for (int r = 0; r < 4; ++r) {
        float p = sigm(dacc[r]) * wo;
        p += __shfl_xor(p, 1, 64);
        p += __shfl_xor(p, 2, 64);
        p += __shfl_xor(p, 4, 64);
        p += __shfl_xor(p, 8, 64);     // sum over m (16 units of this wave)
        if (m == 0) psum[w][q * 4 + r] = p;
    }
    __syncthreads();
    if (tid < 16) {
        float s = psum[0][tid] + psum[1][tid] + psum[2][tid] + psum[3][tid] + bo[0];
        out[b0 + tid] = sigm(s);
    }
}

extern "C" void kernel_launch(void* const* d_in, const int* in_sizes, int n_in,
                              void* d_out, int out_size, void* d_ws, size_t ws_size,
                              hipStream_t stream) {
    (void)in_sizes; (void)n_in; (void)d_ws; (void)ws_size; (void)out_size;
    const float* x  = (const float*)d_in[0];
    const float* W1 = (const float*)d_in[1];
    const float* U1 = (const float*)d_in[2];
    const float* b1 = (const float*)d_in[3];
    const float* W2 = (const float*)d_in[4];
    const float* U2 = (const float*)d_in[5];
    const float* b2 = (const float*)d_in[6];
    const float* Wd = (const float*)d_in[7];
    const float* bd = (const float*)d_in[8];
    const float* Wo = (const float*)d_in[9];
    const float* bo = (const float*)d_in[10];
    lstm2_mfma<<<dim3(256), dim3(256), 0, stream>>>(
        x, W1, U1, b1, W2, U2, b2, Wd, bd, Wo, bo, (float*)d_out);
}

// Round 4
// 356.016 us; speedup vs baseline: 7.6625x; 1.2787x over previous
//
#include <hip/hip_runtime.h>

// Fused 2-layer LSTM (H=64) + Dense(64,sigmoid) + Dense(1,sigmoid), MFMA bf16,
// layer-pipelined across wave groups.
// B=4096, T=256, F=32. One WG = 512 threads = 8 waves handles BB=16 batch rows.
// Waves 0-3 (group A): layer 1 for step u.  Waves 4-7 (group B): layer 2 for
// step u-1 (needs h1[u-1], h2[u-2] only). One barrier per step; double-buffered
// h1/h2/x in LDS as bf16 (row stride 72 shorts, conflict-free b128 A-frags).
// Activation scales folded into weights: gates i,f,o scaled by -log2e
// (sigm = rcp(1+exp2(z'))), gate g by +2*log2e (tanh = 1-2*rcp(1+exp2(z'))).
// Cell state kept pre-scaled by 2*log2e so tanh(c) needs no input mul.
// MFMA 16x16x32 layouts (learn_hip-verified):
//   A[m=lane&15][k=(lane>>4)*8+j], B[k=(lane>>4)*8+j][n=lane&15],
//   C/D: col=lane&15, row=(lane>>4)*4+reg.

typedef __attribute__((ext_vector_type(8))) short short8;
typedef __attribute__((ext_vector_type(4))) float floatx4;
typedef __attribute__((ext_vector_type(2))) float floatx2;

__device__ __forceinline__ float ex2(float x){ return __builtin_amdgcn_exp2f(x); }
__device__ __forceinline__ float rcp_(float x){ return __builtin_amdgcn_rcpf(x); }
__device__ __forceinline__ float sigm(float x){ return rcp_(1.0f + ex2(-1.44269504f*x)); }
__device__ __forceinline__ unsigned bfbits(float f){       // RNE f32->bf16 (raw bits)
    unsigned u = __builtin_bit_cast(unsigned, f);
    u += 0x7FFFu + ((u >> 16) & 1u);
    return u >> 16;
}
__device__ __forceinline__ short f2bf(float f){ return (short)bfbits(f); }
__device__ __forceinline__ unsigned pack_bf2(float a, float b){
    return bfbits(a) | (bfbits(b) << 16);
}

#define MFMA_BF16 __builtin_amdgcn_mfma_f32_16x16x32_bf16

__global__ __launch_bounds__(512, 1)
void lstm2_pipe(const float* __restrict__ x,
                const float* __restrict__ W1, const float* __restrict__ U1, const float* __restrict__ b1,
                const float* __restrict__ W2, const float* __restrict__ U2, const float* __restrict__ b2,
                const float* __restrict__ Wd, const float* __restrict__ bd,
                const float* __restrict__ Wo, const float* __restrict__ bo,
                float* __restrict__ out)
{
    __shared__ __align__(16) short h1b[2][16 * 72];
    __shared__ __align__(16) short h2b[2][16 * 72];
    __shared__ __align__(16) short xsb[2][16 * 40];
    __shared__ float psum[4][16];

    const int tid  = threadIdx.x;
    const int w    = tid >> 6;            // 0..7
    const bool isA = (w < 4);
    const int wv   = isA ? w : (w - 4);   // column-wave 0..3
    const int lane = tid & 63;
    const int m    = lane & 15;
    const int q    = lane >> 4;
    const int b0   = blockIdx.x * 16;
    const int col  = wv * 16 + m;         // unit 0..63

    const float LG  = 1.44269504f;        // log2(e)

    // ---- weight B-fragments -> registers, activation scale folded in ----
    // A uses Wf[g*3+{0,1,2}] (12 frags); B uses Wf[g*4+{0..3}] (16 frags).
    short8 Wf[16];
    float  bg[4];
    if (isA) {
#pragma unroll
        for (int g = 0; g < 4; ++g) {
            const float s = (g == 2) ? (2.0f * LG) : (-LG);
            const int n = g * 64 + col;
            bg[g] = b1[n] * s;
#pragma unroll
            for (int j = 0; j < 8; ++j) {
                const int k = q * 8 + j;
                Wf[g * 3 + 0][j] = f2bf(W1[k * 256 + n] * s);
                Wf[g * 3 + 1][j] = f2bf(U1[k * 256 + n] * s);
                Wf[g * 3 + 2][j] = f2bf(U1[(32 + k) * 256 + n] * s);
            }
        }
    } else {
#pragma unroll
        for (int g = 0; g < 4; ++g) {
            const float s = (g == 2) ? (2.0f * LG) : (-LG);
            const int n = g * 64 + col;
            bg[g] = b2[n] * s;
#pragma unroll
            for (int j = 0; j < 8; ++j) {
                const int k = q * 8 + j;
                Wf[g * 4 + 0][j] = f2bf(W2[k * 256 + n] * s);
                Wf[g * 4 + 1][j] = f2bf(W2[(32 + k) * 256 + n] * s);
                Wf[g * 4 + 2][j] = f2bf(U2[k * 256 + n] * s);
                Wf[g * 4 + 3][j] = f2bf(U2[(32 + k) * 256 + n] * s);
            }
        }
    }

    // ---- zero h double-buffers ----
    {
        unsigned* p1 = (unsigned*)&h1b[0][0];
        unsigned* p2 = (unsigned*)&h2b[0][0];
        for (int i = tid; i < 1152; i += 512) { p1[i] = 0u; p2[i] = 0u; }
    }

    // ---- x staging (group A threads): 2 fp32 per thread per step ----
    const int xr = tid >> 4;              // 0..15 (valid for A's tid<256)
    const int xc = (tid & 15) * 2;
    const float* xrow = x + (size_t)(b0 + xr) * 8192 + xc;   // T*F = 8192
    floatx2 xv0;
    if (isA) {
        floatx2 v = *(const floatx2*)xrow;                    // x[0]
        *(unsigned*)&xsb[0][xr * 40 + xc] = pack_bf2(v.x, v.y);
        xv0 = *(const floatx2*)(xrow + 32);                   // x[1]
    }
    __syncthreads();

    float c[4] = {0, 0, 0, 0};            // cell state, pre-scaled by 2*log2e

    for (int u = 0; u <= 256; ++u) {
        const int par = u & 1, pax = par ^ 1;
        if (isA) {
            if (u < 256) {
                // ---- layer 1, step u: z = [x_u | h1_{u-1}] @ [W1;U1] ----
                short8 a0 = *(const short8*)&xsb[par][m * 40 + q * 8];
                short8 a1 = *(const short8*)&h1b[pax][m * 72 + q * 8];
                short8 a2 = *(const short8*)&h1b[pax][m * 72 + 32 + q * 8];
                floatx4 z[4];
#pragma unroll
                for (int g = 0; g < 4; ++g) {
                    floatx4 acc = { bg[g], bg[g], bg[g], bg[g] };
                    acc = MFMA_BF16(a0, Wf[g * 3 + 0], acc, 0, 0, 0);
                    acc = MFMA_BF16(a1, Wf[g * 3 + 1], acc, 0, 0, 0);
                    acc = MFMA_BF16(a2, Wf[g * 3 + 2], acc, 0, 0, 0);
                    z[g] = acc;
                }
                float hv[4];
#pragma unroll
                for (int r = 0; r < 4; ++r) {
                    float iv = rcp_(1.0f + ex2(z[0][r]));
                    float fv = rcp_(1.0f + ex2(z[1][r]));
                    float rg = rcp_(1.0f + ex2(z[2][r]));
                    float ov = rcp_(1.0f + ex2(z[3][r]));
                    float gp = fmaf(-5.77078016f, rg, 2.88539008f);  // 2LG*tanh
                    c[r] = fmaf(fv, c[r], iv * gp);
                    float th = fmaf(-2.0f, rcp_(1.0f + ex2(c[r])), 1.0f);
                    hv[r] = ov * th;
                }
                unsigned p01 = pack_bf2(hv[0], hv[1]);
                unsigned p23 = pack_bf2(hv[2], hv[3]);
                short* hw = &h1b[par][(q * 4) * 72 + col];
                hw[0]       = (short)(p01 & 0xFFFF);
                hw[72]      = (short)(p01 >> 16);
                hw[144]     = (short)(p23 & 0xFFFF);
                hw[216]     = (short)(p23 >> 16);
                // stage x[u+1] into other buffer; prefetch x[u+2]
                if (u < 255) {
                    *(unsigned*)&xsb[pax][xr * 40 + xc] = pack_bf2(xv0.x, xv0.y);
                    if (u < 254) xv0 = *(const floatx2*)(xrow + (size_t)(u + 2) * 32);
                }
            }
        } else {
            if (u >= 1) {
                // ---- layer 2, step t=u-1: z = [h1_t | h2_{t-1}] @ [W2;U2] ----
                // h1[t] in h1b[pax]; h2[t-1] in h2b[par]; write h2[t] -> h2b[pax]
                short8 g0 = *(const short8*)&h1b[pax][m * 72 + q * 8];
                short8 g1 = *(const short8*)&h1b[pax][m * 72 + 32 + q * 8];
                short8 g2 = *(const short8*)&h2b[par][m * 72 + q * 8];
                short8 g3 = *(const short8*)&h2b[par][m * 72 + 32 + q * 8];
                floatx4 z[4];
#pragma unroll
                for (int g = 0; g < 4; ++g) {
                    floatx4 acc = { bg[g], bg[g], bg[g], bg[g] };
                    acc = MFMA_BF16(g0, Wf[g * 4 + 0], acc, 0, 0, 0);
                    acc = MFMA_BF16(g1, Wf[g * 4 + 1], acc, 0, 0, 0);
                    acc = MFMA_BF16(g2, Wf[g * 4 + 2], acc, 0, 0, 0);
                    acc = MFMA_BF16(g3, Wf[g * 4 + 3], acc, 0, 0, 0);
                    z[g] = acc;
                }
                float hv[4];
#pragma unroll
                for (int r = 0; r < 4; ++r) {
                    float iv = rcp_(1.0f + ex2(z[0][r]));
                    float fv = rcp_(1.0f + ex2(z[1][r]));
                    float rg = rcp_(1.0f + ex2(z[2][r]));
                    float ov = rcp_(1.0f + ex2(z[3][r]));
                    float gp = fmaf(-5.77078016f, rg, 2.88539008f);
                    c[r] = fmaf(fv, c[r], iv * gp);
                    float th = fmaf(-2.0f, rcp_(1.0f + ex2(c[r])), 1.0f);
                    hv[r] = ov * th;
                }
                unsigned p01 = pack_bf2(hv[0], hv[1]);
                unsigned p23 = pack_bf2(hv[2], hv[3]);
                short* hw = &h2b[pax][(q * 4) * 72 + col];
                hw[0]       = (short)(p01 & 0xFFFF);
                hw[72]      = (short)(p01 >> 16);
                hw[144]     = (short)(p23 & 0xFFFF);
                hw[216]     = (short)(p23 >> 16);
            }
        }
        __syncthreads();
    }

    // ---- epilogue (group B): h_last = h2[255] in h2b[1] ----
    if (!isA) {
        short8 wd0, wd1;
#pragma unroll
        for (int j = 0; j < 8; ++j) {
            wd0[j] = f2bf(Wd[(q * 8 + j) * 64 + col] * (-LG));
            wd1[j] = f2bf(Wd[(32 + q * 8 + j) * 64 + col] * (-LG));
        }
        short8 hA0 = *(const short8*)&h2b[1][m * 72 + q * 8];
        short8 hA1 = *(const short8*)&h2b[1][m * 72 + 32 + q * 8];
        const float bdv = bd[col] * (-LG);
        floatx4 dacc = { bdv, bdv, bdv, bdv };
        dacc = MFMA_BF16(hA0, wd0, dacc, 0, 0, 0);
        dacc = MFMA_BF16(hA1, wd1, dacc, 0, 0, 0);
        const float wo = Wo[col];
#pragma unroll
        for (int r = 0; r < 4; ++r) {
            float p = rcp_(1.0f + ex2(dacc[r])) * wo;   // sigm (scale folded)
            p += __shfl_xor(p, 1, 64);
            p += __shfl_xor(p, 2, 64);
            p += __shfl_xor(p, 4, 64);
            p += __shfl_xor(p, 8, 64);                  // sum over this wave's 16 units
            if (m == 0) psum[wv][q * 4 + r] = p;
        }
    }
    __syncthreads();
    if (tid >= 256 && tid < 272) {
        const int i = tid - 256;
        float s = psum[0][i] + psum[1][i] + psum[2][i] + psum[3][i] + bo[0];
        out[b0 + i] = sigm(s);
    }
}

extern "C" void kernel_launch(void* const* d_in, const int* in_sizes, int n_in,
                              void* d_out, int out_size, void* d_ws, size_t ws_size,
                              hipStream_t stream) {
    (void)in_sizes; (void)n_in; (void)d_ws; (void)ws_size; (void)out_size;
    const float* x  = (const float*)d_in[0];
    const float* W1 = (const float*)d_in[1];
    const float* U1 = (const float*)d_in[2];
    const float* b1 = (const float*)d_in[3];
    const float* W2 = (const float*)d_in[4];
    const float* U2 = (const float*)d_in[5];
    const float* b2 = (const float*)d_in[6];
    const float* Wd = (const float*)d_in[7];
    const float* bd = (const float*)d_in[8];
    const float* Wo = (const float*)d_in[9];
    const float* bo = (const float*)d_in[10];
    lstm2_pipe<<<dim3(256), dim3(512), 0, stream>>>(
        x, W1, U1, b1, W2, U2, b2, Wd, bd, Wo, bo, (float*)d_out);
}

// Round 5
// 343.710 us; speedup vs baseline: 7.9368x; 1.0358x over previous
//
#include <hip/hip_runtime.h>

// Fused 2-layer LSTM (H=64) + Dense(64,sigmoid) + Dense(1,sigmoid), MFMA bf16.
// Transposed-z formulation: z^T[gate-unit, batch] = Wt @ [x|h]^T so each lane
// owns ALL FOUR gates of a cell (2 cells/lane), halving per-wave gate VALU.
// B=4096, T=256, F=32. One WG = 1024 threads = 16 waves handles BB=16 rows.
// Waves 0-7 (L1): layer 1 step u, 2 M-tiles each (tiles = 4 units x 4 gates,
// row = unit_local*4 + gate). Waves 8-15 (L2): layer 2 step u-1. One barrier
// per step; double-buffered h1/h2/x in LDS as bf16 (row stride 72 shorts).
// Activation scales folded into weights (i,f,o: -log2e; g: +2*log2e); cell
// state kept pre-scaled by 2*log2e. Bias enters as the MFMA C operand.
// MFMA 16x16x32 layouts (learn_hip-verified):
//   A[m=lane&15][k=(lane>>4)*8+j], B[k=(lane>>4)*8+j][n=lane&15],
//   C/D: col=lane&15, row=(lane>>4)*4+reg.

typedef __attribute__((ext_vector_type(8))) short short8;
typedef __attribute__((ext_vector_type(4))) float floatx4;
typedef __attribute__((ext_vector_type(2))) float floatx2;

__device__ __forceinline__ float ex2(float x){ return __builtin_amdgcn_exp2f(x); }
__device__ __forceinline__ float rcp_(float x){ return __builtin_amdgcn_rcpf(x); }
__device__ __forceinline__ float sigm(float x){ return rcp_(1.0f + ex2(-1.44269504f*x)); }
__device__ __forceinline__ unsigned bfbits(float f){       // RNE f32->bf16 (raw bits)
    unsigned u = __builtin_bit_cast(unsigned, f);
    u += 0x7FFFu + ((u >> 16) & 1u);
    return u >> 16;
}
__device__ __forceinline__ short f2bf(float f){ return (short)bfbits(f); }
__device__ __forceinline__ unsigned pack_bf2(float a, float b){
    return bfbits(a) | (bfbits(b) << 16);
}

#define MFMA_BF16 __builtin_amdgcn_mfma_f32_16x16x32_bf16

__global__ __launch_bounds__(1024, 1)
void lstm2_tz(const float* __restrict__ x,
              const float* __restrict__ W1, const float* __restrict__ U1, const float* __restrict__ b1,
              const float* __restrict__ W2, const float* __restrict__ U2, const float* __restrict__ b2,
              const float* __restrict__ Wd, const float* __restrict__ bd,
              const float* __restrict__ Wo, const float* __restrict__ bo,
              float* __restrict__ out)
{
    __shared__ __align__(16) short h1b[2][16 * 72];   // [buf][batch*72 + unit]
    __shared__ __align__(16) short h2b[2][16 * 72];
    __shared__ __align__(16) short xsb[2][16 * 40];   // [buf][batch*40 + feat]
    __shared__ float psum[4][16];

    const int tid  = threadIdx.x;
    const int w    = tid >> 6;            // 0..15
    const bool isL1 = (w < 8);
    const int wv   = isL1 ? w : (w - 8);  // 0..7 within group
    const int lane = tid & 63;
    const int n    = lane & 15;           // B-frag col = batch row; also A-frag m
    const int q    = lane >> 4;           // quad
    const int b0   = blockIdx.x * 16;

    const float LG = 1.44269504f;         // log2(e)

    // A-frag row mapping: within-tile row m -> (unit_local = m>>2, gate = m&3)
    const int ugl = n >> 2;
    const int gA  = n & 3;
    const float sA = (gA == 2) ? (2.0f * LG) : (-LG);

    // ---- one-time: weight A-fragments + bias C vectors ----
    short8  Wa[8];
    floatx4 bC[2];
    if (isL1) {
#pragma unroll
        for (int tt = 0; tt < 2; ++tt) {
            const int t = wv * 2 + tt;
            const int ncol = gA * 64 + t * 4 + ugl;
#pragma unroll
            for (int j = 0; j < 8; ++j) {
                const int k = q * 8 + j;
                Wa[tt * 3 + 0][j] = f2bf(W1[k * 256 + ncol] * sA);
                Wa[tt * 3 + 1][j] = f2bf(U1[k * 256 + ncol] * sA);
                Wa[tt * 3 + 2][j] = f2bf(U1[(32 + k) * 256 + ncol] * sA);
            }
#pragma unroll
            for (int r = 0; r < 4; ++r)
                bC[tt][r] = b1[r * 64 + t * 4 + q] * ((r == 2) ? (2.0f * LG) : (-LG));
        }
    } else {
#pragma unroll
        for (int tt = 0; tt < 2; ++tt) {
            const int t = wv * 2 + tt;
            const int ncol = gA * 64 + t * 4 + ugl;
#pragma unroll
            for (int j = 0; j < 8; ++j) {
                const int k = q * 8 + j;
                Wa[tt * 4 + 0][j] = f2bf(W2[k * 256 + ncol] * sA);
                Wa[tt * 4 + 1][j] = f2bf(W2[(32 + k) * 256 + ncol] * sA);
                Wa[tt * 4 + 2][j] = f2bf(U2[k * 256 + ncol] * sA);
                Wa[tt * 4 + 3][j] = f2bf(U2[(32 + k) * 256 + ncol] * sA);
            }
#pragma unroll
            for (int r = 0; r < 4; ++r)
                bC[tt][r] = b2[r * 64 + t * 4 + q] * ((r == 2) ? (2.0f * LG) : (-LG));
        }
    }

    // ---- zero h double-buffers ----
    {
        unsigned* p1 = (unsigned*)&h1b[0][0];
        unsigned* p2 = (unsigned*)&h2b[0][0];
        for (int i = tid; i < 1152; i += 1024) { p1[i] = 0u; p2[i] = 0u; }
    }

    // ---- x staging (tid<256, waves 0-3): 2 fp32 of row (tid>>4) per step ----
    const int xr = tid >> 4;
    const int xc = (tid & 15) * 2;
    const float* xrow = x + (size_t)(b0 + xr) * 8192 + xc;   // T*F = 8192
    floatx2 xv0;
    if (tid < 256) {
        floatx2 v = *(const floatx2*)xrow;                    // x[0]
        *(unsigned*)&xsb[0][xr * 40 + xc] = pack_bf2(v.x, v.y);
        xv0 = *(const floatx2*)(xrow + 32);                   // x[1]
    }
    __syncthreads();

    float c[2] = {0, 0};                  // cell state, pre-scaled by 2*log2e

    for (int u = 0; u <= 256; ++u) {
        const int par = u & 1, pax = par ^ 1;
        if (isL1) {
            if (u < 256) {
                // ---- layer 1, step u: z^T = Wt @ [x_u | h1_{u-1}]^T ----
                short8 bx  = *(const short8*)&xsb[par][n * 40 + q * 8];
                short8 bh0 = *(const short8*)&h1b[pax][n * 72 + q * 8];
                short8 bh1 = *(const short8*)&h1b[pax][n * 72 + 32 + q * 8];
#pragma unroll
                for (int tt = 0; tt < 2; ++tt) {
                    floatx4 z = bC[tt];
                    z = MFMA_BF16(Wa[tt * 3 + 0], bx,  z, 0, 0, 0);
                    z = MFMA_BF16(Wa[tt * 3 + 1], bh0, z, 0, 0, 0);
                    z = MFMA_BF16(Wa[tt * 3 + 2], bh1, z, 0, 0, 0);
                    float iv = rcp_(1.0f + ex2(z[0]));
                    float fv = rcp_(1.0f + ex2(z[1]));
                    float rg = rcp_(1.0f + ex2(z[2]));
                    float ov = rcp_(1.0f + ex2(z[3]));
                    float gp = fmaf(-5.77078016f, rg, 2.88539008f);  // 2LG*tanh
                    c[tt] = fmaf(fv, c[tt], iv * gp);
                    float th = fmaf(-2.0f, rcp_(1.0f + ex2(c[tt])), 1.0f);
                    h1b[par][n * 72 + (wv * 2 + tt) * 4 + q] = f2bf(ov * th);
                }
                // stage x[u+1] into other buffer; prefetch x[u+2]
                if (tid < 256 && u < 255) {
                    *(unsigned*)&xsb[pax][xr * 40 + xc] = pack_bf2(xv0.x, xv0.y);
                    if (u < 254) xv0 = *(const floatx2*)(xrow + (size_t)(u + 2) * 32);
                }
            }
        } else {
            if (u >= 1) {
                // ---- layer 2, step t=u-1: z^T = Wt @ [h1_t | h2_{t-1}]^T ----
                short8 bh0 = *(const short8*)&h1b[pax][n * 72 + q * 8];
                short8 bh1 = *(const short8*)&h1b[pax][n * 72 + 32 + q * 8];
                short8 bg0 = *(const short8*)&h2b[par][n * 72 + q * 8];
                short8 bg1 = *(const short8*)&h2b[par][n * 72 + 32 + q * 8];
#pragma unroll
                for (int tt = 0; tt < 2; ++tt) {
                    floatx4 z = bC[tt];
                    z = MFMA_BF16(Wa[tt * 4 + 0], bh0, z, 0, 0, 0);
                    z = MFMA_BF16(Wa[tt * 4 + 1], bh1, z, 0, 0, 0);
                    z = MFMA_BF16(Wa[tt * 4 + 2], bg0, z, 0, 0, 0);
                    z = MFMA_BF16(Wa[tt * 4 + 3], bg1, z, 0, 0, 0);
                    float iv = rcp_(1.0f + ex2(z[0]));
                    float fv = rcp_(1.0f + ex2(z[1]));
                    float rg = rcp_(1.0f + ex2(z[2]));
                    float ov = rcp_(1.0f + ex2(z[3]));
                    float gp = fmaf(-5.77078016f, rg, 2.88539008f);
                    c[tt] = fmaf(fv, c[tt], iv * gp);
                    float th = fmaf(-2.0f, rcp_(1.0f + ex2(c[tt])), 1.0f);
                    h2b[pax][n * 72 + (wv * 2 + tt) * 4 + q] = f2bf(ov * th);
                }
            }
        }
        __syncthreads();
    }

    // ---- epilogue (waves 8-11): h_last = h2[255] in h2b[1] ----
    // Dense(64,sigmoid) in the round-4 verified orientation (A = h2 rows).
    if (!isL1 && wv < 4) {
        const int colD = wv * 16 + n;
        short8 wd0, wd1;
#pragma unroll
        for (int j = 0; j < 8; ++j) {
            wd0[j] = f2bf(Wd[(q * 8 + j) * 64 + colD] * (-LG));
            wd1[j] = f2bf(Wd[(32 + q * 8 + j) * 64 + colD] * (-LG));
        }
        short8 hA0 = *(const short8*)&h2b[1][n * 72 + q * 8];
        short8 hA1 = *(const short8*)&h2b[1][n * 72 + 32 + q * 8];
        const float bdv = bd[colD] * (-LG);
        floatx4 dacc = { bdv, bdv, bdv, bdv };
        dacc = MFMA_BF16(hA0, wd0, dacc, 0, 0, 0);
        dacc = MFMA_BF16(hA1, wd1, dacc, 0, 0, 0);
        const float wo = Wo[colD];
#pragma unroll
        for (int r = 0; r < 4; ++r) {
            float p = rcp_(1.0f + ex2(dacc[r])) * wo;   // sigm (scale folded)
            p += __shfl_xor(p, 1, 64);
            p += __shfl_xor(p, 2, 64);
            p += __shfl_xor(p, 4, 64);
            p += __shfl_xor(p, 8, 64);                  // sum over 16 dense units
            if (n == 0) psum[wv][q * 4 + r] = p;
        }
    }
    __syncthreads();
    if (tid < 16) {
        float s = psum[0][tid] + psum[1][tid] + psum[2][tid] + psum[3][tid] + bo[0];
        out[b0 + tid] = sigm(s);
    }
}

extern "C" void kernel_launch(void* const* d_in, const int* in_sizes, int n_in,
                              void* d_out, int out_size, void* d_ws, size_t ws_size,
                              hipStream_t stream) {
    (void)in_sizes; (void)n_in; (void)d_ws; (void)ws_size; (void)out_size;
    const float* x  = (const float*)d_in[0];
    const float* W1 = (const float*)d_in[1];
    const float* U1 = (const float*)d_in[2];
    const float* b1 = (const float*)d_in[3];
    const float* W2 = (const float*)d_in[4];
    const float* U2 = (const float*)d_in[5];
    const float* b2 = (const float*)d_in[6];
    const float* Wd = (const float*)d_in[7];
    const float* bd = (const float*)d_in[8];
    const float* Wo = (const float*)d_in[9];
    const float* bo = (const float*)d_in[10];
    lstm2_tz<<<dim3(256), dim3(1024), 0, stream>>>(
        x, W1, U1, b1, W2, U2, b2, Wd, bd, Wo, bo, (float*)d_out);
}